// Round 5
// baseline (235.358 us; speedup 1.0000x reference)
//
#include <hip/hip_runtime.h>
#include <hip/hip_bf16.h>

#define B_ 8192
#define I_ 512
#define H_ 1024
#define R_ 64

typedef __bf16 bf16x8 __attribute__((ext_vector_type(8)));
typedef short  s16x8  __attribute__((ext_vector_type(8)));
typedef float  f32x4  __attribute__((ext_vector_type(4)));

static __device__ __forceinline__ short f2bf(float f) {
    union { float f; unsigned u; } v; v.f = f;
    unsigned r = v.u + 0x7fffu + ((v.u >> 16) & 1u);
    return (short)(r >> 16);
}
// v_rcp_f32 (~1 ulp) instead of IEEE divide (no -ffast-math in harness).
static __device__ __forceinline__ float frcp_(float x) {
#if __has_builtin(__builtin_amdgcn_rcpf)
    return __builtin_amdgcn_rcpf(x);
#else
    float r; asm("v_rcp_f32 %0, %1" : "=v"(r) : "v"(x)); return r;
#endif
}
static __device__ __forceinline__ float sigmoidf_(float v) {
    return frcp_(1.f + __expf(-v));
}
static __device__ __forceinline__ float tanhf_(float v) {
    return 2.f * frcp_(1.f + __expf(-2.f * v)) - 1.f;
}

// ---------------------------------------------------------------------------
// Prep: uxT[64][512], uhT[64][1024], Vc[4096][128] (bf16), and the folded
// per-j epilogue tables (f32, [4][1024] each):
//   AX[g][j] = dia_x[j] - coef_x[g][j]   (0 for j >= 512)
//   AH[g][j] = dia_h[j] - coef_h[g][j]
//   BS[g][j] = b_x[g*H+j] + b_h[g*H+j]
// Coef section: one wave per j, lanes = rank r.
// 32768 + 65536 + 524288 + 98304 = 720896 = 2816 * 256 threads.
// ---------------------------------------------------------------------------
__global__ __launch_bounds__(256) void prep_kernel(
    const float* __restrict__ u_x, const float* __restrict__ u_h,
    const float* __restrict__ v_x, const float* __restrict__ v_h,
    const float* __restrict__ b_x, const float* __restrict__ b_h,
    const float* __restrict__ dia_x, const float* __restrict__ dia_h,
    short* __restrict__ uxT, short* __restrict__ uhT, short* __restrict__ Vc,
    float* __restrict__ AX, float* __restrict__ AH, float* __restrict__ BS)
{
    int t = blockIdx.x * 256 + threadIdx.x;
    if (t < 64 * 512) {                       // uxT[r][k] = u_x[k][r], coalesced read
        int k = t >> 6, r = t & 63;
        uxT[r * 512 + k] = f2bf(u_x[t]);
        return;
    }
    t -= 64 * 512;
    if (t < 64 * 1024) {                      // uhT[r][k] = u_h[k][r]
        int k = t >> 6, r = t & 63;
        uhT[r * 1024 + k] = f2bf(u_h[t]);
        return;
    }
    t -= 64 * 1024;
    if (t < 4096 * 128) {                     // Vc = [v_x | v_h] rows, bf16
        int n = t >> 7, q = t & 127;
        Vc[t] = f2bf(q < 64 ? v_x[n * 64 + q] : v_h[n * 64 + (q - 64)]);
        return;
    }
    t -= 4096 * 128;
    if (t < 1536 * 64) {                      // coef reductions: 1536 waves, one j each
        const int wid = t >> 6, lane = t & 63;
        const float* U; const float* V; int j;
        const bool isx = (wid < 512);
        if (isx) { U = u_x; V = v_x; j = wid;       }
        else     { U = u_h; V = v_h; j = wid - 512; }
        const float uv = U[(size_t)j * 64 + lane];
        float s[4];
#pragma unroll
        for (int g = 0; g < 4; ++g)
            s[g] = uv * V[(size_t)(g * H_ + j) * 64 + lane];
#pragma unroll
        for (int off = 32; off >= 1; off >>= 1)
#pragma unroll
            for (int g = 0; g < 4; ++g)
                s[g] += __shfl_xor(s[g], off, 64);
        if (lane == 0) {
            if (isx) {
#pragma unroll
                for (int g = 0; g < 4; ++g)
                    AX[g * 1024 + j] = dia_x[j] - s[g];
            } else {
#pragma unroll
                for (int g = 0; g < 4; ++g) {
                    AH[g * 1024 + j] = dia_h[j] - s[g];
                    BS[g * 1024 + j] = b_x[g * H_ + j] + b_h[g * H_ + j];
                    if (j >= 512) AX[g * 1024 + j] = 0.f;
                }
            }
        }
        return;
    }
}

// ---------------------------------------------------------------------------
// Stage 1: P[b][0:64] = x @ u_x, P[b][64:128] = h @ u_h  (bf16 MFMA).
// 256-thr blocks (4 waves), 16 batch rows per block -> grid (512, 2).
// ---------------------------------------------------------------------------
__global__ __launch_bounds__(256) void stage1_kernel(
    const float* __restrict__ x, const float* __restrict__ h,
    const short* __restrict__ uxT, const short* __restrict__ uhT,
    short* __restrict__ P)
{
    __shared__ short At[16 * 136];
    const int w = threadIdx.x >> 6, lane = threadIdx.x & 63;
    const int quad = lane >> 4, lr = lane & 15;
    const int n0 = w * 16;

    const float* X; const short* UT; int K, co;
    if (blockIdx.y == 0) { X = x; UT = uxT; K = I_; co = 0; }
    else                 { X = h; UT = uhT; K = H_; co = 64; }

    const int b0 = blockIdx.x * 16;
    const int srow = threadIdx.x >> 4;
    const int scol = (threadIdx.x & 15) * 8;

    f32x4 acc = {};
    const short* bp = UT + (size_t)(n0 + lr) * K + quad * 8;
    const short* arow = At + lr * 136 + quad * 8;
    const float* srcbase = X + (size_t)(b0 + srow) * K + scol;

    float4 c0 = ((const float4*)(srcbase))[0];
    float4 c1 = ((const float4*)(srcbase))[1];

    for (int k0 = 0; k0 < K; k0 += 128) {
        s16x8 p;
        p[0] = f2bf(c0.x); p[1] = f2bf(c0.y); p[2] = f2bf(c0.z); p[3] = f2bf(c0.w);
        p[4] = f2bf(c1.x); p[5] = f2bf(c1.y); p[6] = f2bf(c1.z); p[7] = f2bf(c1.w);
        __syncthreads();
        *(s16x8*)(At + srow * 136 + scol) = p;
        __syncthreads();
        if (k0 + 128 < K) {
            c0 = ((const float4*)(srcbase + k0 + 128))[0];
            c1 = ((const float4*)(srcbase + k0 + 128))[1];
        }
#pragma unroll
        for (int ks = 0; ks < 4; ++ks) {
            bf16x8 bfrag = *(const bf16x8*)(bp + k0 + ks * 32);
            bf16x8 afrag = *(const bf16x8*)(arow + ks * 32);
            acc = __builtin_amdgcn_mfma_f32_16x16x32_bf16(afrag, bfrag, acc, 0, 0, 0);
        }
    }

#pragma unroll
    for (int r = 0; r < 4; ++r)
        P[(size_t)(b0 + quad * 4 + r) * 128 + co + n0 + lr] = f2bf(acc[r]);
}

// ---------------------------------------------------------------------------
// Stage 2: gates = Vc @ P^T (swapped operands, verified in R4) + LSTM epilogue.
// RESTRUCTURE vs R4: each block owns 32 FULL batch rows (all 1024 j).
// 512 threads = 8 independent waves (no LDS, no barriers): wave = (rowgrp,
// jgrp); rowgrp in {0,1} picks 16 rows, jgrp in {0..3} picks a 256-wide
// j-range walked as 16 j-tiles. P fragments (B-operand) are loaded ONCE per
// wave and reused across all 16 tiles; Vc streams from L2 (1 MB/block).
// WHY: R0-R4 all plateaued at ~2 TB/s with every pipe idle. Their common
// trait: each wave touched 64 B-per-row chunks at 4 KB stride, with the 16
// blocks covering one row's page running at uncorrelated times on different
// XCDs -> DRAM page thrash. Now every x/h/c/out row's 4 KB page is consumed
// start-to-finish by ONE CU (16 open pages/array/block).
// Epilogue uses prefolded tables: g = acc + xe*AX + he*AH + BS.
// Plain stores (NT amplified WRITE_SIZE 66->80 MB in R4 -- reverted).
// Grid: 256 blocks = exactly 1/CU.
// ---------------------------------------------------------------------------
__global__ __launch_bounds__(512) void stage2_kernel(
    const short* __restrict__ P, const short* __restrict__ Vc,
    const float* __restrict__ x, const float* __restrict__ h,
    const float* __restrict__ c,
    const float* __restrict__ AX, const float* __restrict__ AH,
    const float* __restrict__ BS,
    float* __restrict__ out)
{
    const int tid  = threadIdx.x;
    const int lane = tid & 63, wv = tid >> 6;
    const int quad = lane >> 4, lr = lane & 15;
    const int rowg = wv >> 2, jg = wv & 3;
    const int row  = blockIdx.x * 32 + rowg * 16 + lr;   // this lane's batch row
    const int jbase = jg * 256;                          // wave's 256-wide j-range
    const bool jx = (jg < 2);                            // wave-uniform: j < 512

    // B-operand: P row fragments — loaded ONCE, reused for all 16 j-tiles
    bf16x8 a[4];
#pragma unroll
    for (int ks = 0; ks < 4; ++ks)
        a[ks] = *(const bf16x8*)(P + (size_t)row * 128 + ks * 32 + quad * 8);

    // prologue: x/h/c for tile 0
    f32x4 xv = {}, hv, cv;
    {
        const int j4 = jbase + quad * 4;
        cv = *(const f32x4*)(c + (size_t)row * H_ + j4);
        hv = *(const f32x4*)(h + (size_t)row * H_ + j4);
        if (jx) xv = *(const f32x4*)(x + (size_t)row * I_ + j4);
    }

    for (int t = 0; t < 16; ++t) {
        const int jt = jbase + t * 16;
        const int j4 = jt + quad * 4;

        // A-operand: Vc fragments for this j-tile (L2-hot, 1 MB/block total)
        bf16x8 vfr[4][4];
#pragma unroll
        for (int g = 0; g < 4; ++g)
#pragma unroll
            for (int ks = 0; ks < 4; ++ks)
                vfr[g][ks] = *(const bf16x8*)(Vc + (size_t)(g * H_ + jt + lr) * 128 + ks * 32 + quad * 8);

        // folded per-j constants (48 KB tables, L2-hot)
        f32x4 ax[4] = {}, ah[4], bs[4];
#pragma unroll
        for (int g = 0; g < 4; ++g) {
            if (jx) ax[g] = *(const f32x4*)(AX + g * 1024 + j4);
            ah[g] = *(const f32x4*)(AH + g * 1024 + j4);
            bs[g] = *(const f32x4*)(BS + g * 1024 + j4);
        }

        // prefetch next tile's x/h/c (HBM latency hides under MFMA+epilogue)
        f32x4 xn = {}, hn, cn;
        if (t < 15) {
            const int jn = j4 + 16;
            cn = *(const f32x4*)(c + (size_t)row * H_ + jn);
            hn = *(const f32x4*)(h + (size_t)row * H_ + jn);
            if (jx) xn = *(const f32x4*)(x + (size_t)row * I_ + jn);
        }

        // MFMA: D[j][b], operands from registers
        f32x4 acc[4] = {};
#pragma unroll
        for (int ks = 0; ks < 4; ++ks)
#pragma unroll
            for (int g = 0; g < 4; ++g)
                acc[g] = __builtin_amdgcn_mfma_f32_16x16x32_bf16(vfr[g][ks], a[ks], acc[g], 0, 0, 0);

        // epilogue: lane owns (row, j4..j4+3)
        float hw[4], cw[4];
#pragma unroll
        for (int r = 0; r < 4; ++r) {
            const float xe = xv[r], he = hv[r];

            const float g0 = acc[0][r] + xe * ax[0][r] + he * ah[0][r] + bs[0][r];
            const float g1 = acc[1][r] + xe * ax[1][r] + he * ah[1][r] + bs[1][r];
            const float g2 = acc[2][r] + xe * ax[2][r] + he * ah[2][r] + bs[2][r];
            const float g3 = acc[3][r] + xe * ax[3][r] + he * ah[3][r] + bs[3][r];

            const float ig = sigmoidf_(g0);
            const float fg = sigmoidf_(g1);
            const float og = sigmoidf_(g2);
            const float ng = tanhf_(g3);

            cw[r] = fg * cv[r] + ig * ng;
            hw[r] = og * tanhf_(cw[r]);
        }
        f32x4 hq = { hw[0], hw[1], hw[2], hw[3] };
        f32x4 cq = { cw[0], cw[1], cw[2], cw[3] };
        *(f32x4*)(out + (size_t)row * H_ + j4) = hq;
        *(f32x4*)(out + (size_t)B_ * H_ + (size_t)row * H_ + j4) = cq;

        xv = xn; hv = hn; cv = cn;
    }
}

// ---------------------------------------------------------------------------
extern "C" void kernel_launch(void* const* d_in, const int* in_sizes, int n_in,
                              void* d_out, int out_size, void* d_ws, size_t ws_size,
                              hipStream_t stream) {
    const float* x     = (const float*)d_in[0];
    const float* h     = (const float*)d_in[1];
    const float* c     = (const float*)d_in[2];
    const float* u_x   = (const float*)d_in[3];
    const float* u_h   = (const float*)d_in[4];
    const float* v_x   = (const float*)d_in[5];
    const float* v_h   = (const float*)d_in[6];
    const float* b_x   = (const float*)d_in[7];
    const float* b_h   = (const float*)d_in[8];
    const float* dia_x = (const float*)d_in[9];
    const float* dia_h = (const float*)d_in[10];
    float* out = (float*)d_out;

    char* ws = (char*)d_ws;
    short* P   = (short*)(ws);                                       // 2,097,152 B
    short* uxT = (short*)(ws + 2097152);                             //    65,536
    short* uhT = (short*)(ws + 2097152 + 65536);                     //   131,072
    short* Vc  = (short*)(ws + 2097152 + 65536 + 131072);            // 1,048,576
    float* AX  = (float*)(ws + 2097152 + 65536 + 131072 + 1048576);            // 16,384
    float* AH  = (float*)(ws + 2097152 + 65536 + 131072 + 1048576 + 16384);    // 16,384
    float* BS  = (float*)(ws + 2097152 + 65536 + 131072 + 1048576 + 32768);    // 16,384

    prep_kernel<<<2816, 256, 0, stream>>>(u_x, u_h, v_x, v_h, b_x, b_h, dia_x, dia_h,
                                          uxT, uhT, Vc, AX, AH, BS);
    stage1_kernel<<<dim3(512, 2), 256, 0, stream>>>(x, h, uxT, uhT, P);
    stage2_kernel<<<256, 512, 0, stream>>>(P, Vc, x, h, c, AX, AH, BS, out);
}

// Round 6
// 192.836 us; speedup vs baseline: 1.2205x; 1.2205x over previous
//
#include <hip/hip_runtime.h>
#include <hip/hip_bf16.h>

#define B_ 8192
#define I_ 512
#define H_ 1024
#define R_ 64

typedef __bf16 bf16x8 __attribute__((ext_vector_type(8)));
typedef short  s16x8  __attribute__((ext_vector_type(8)));
typedef float  f32x4  __attribute__((ext_vector_type(4)));

static __device__ __forceinline__ short f2bf(float f) {
    union { float f; unsigned u; } v; v.f = f;
    unsigned r = v.u + 0x7fffu + ((v.u >> 16) & 1u);
    return (short)(r >> 16);
}
// v_rcp_f32 (~1 ulp) instead of IEEE divide (no -ffast-math in harness).
static __device__ __forceinline__ float frcp_(float x) {
#if __has_builtin(__builtin_amdgcn_rcpf)
    return __builtin_amdgcn_rcpf(x);
#else
    float r; asm("v_rcp_f32 %0, %1" : "=v"(r) : "v"(x)); return r;
#endif
}
static __device__ __forceinline__ float sigmoidf_(float v) {
    return frcp_(1.f + __expf(-v));
}
static __device__ __forceinline__ float tanhf_(float v) {
    return 2.f * frcp_(1.f + __expf(-2.f * v)) - 1.f;
}

// ---------------------------------------------------------------------------
// Prep: uxT[64][512], uhT[64][1024], Vc[4096][128] (all bf16), coef_x[4][512],
// coef_h[4][1024] (f32). Coef section: one wave per j, lanes = rank r.
// 32768 + 65536 + 524288 + 98304 = 720896 = 2816 * 256 threads.
// (Byte-identical to the R2 version — R4/R5 prep changes reverted.)
// ---------------------------------------------------------------------------
__global__ __launch_bounds__(256) void prep_kernel(
    const float* __restrict__ u_x, const float* __restrict__ u_h,
    const float* __restrict__ v_x, const float* __restrict__ v_h,
    short* __restrict__ uxT, short* __restrict__ uhT, short* __restrict__ Vc,
    float* __restrict__ coef_x, float* __restrict__ coef_h)
{
    int t = blockIdx.x * 256 + threadIdx.x;
    if (t < 64 * 512) {                       // uxT[r][k] = u_x[k][r], coalesced read
        int k = t >> 6, r = t & 63;
        uxT[r * 512 + k] = f2bf(u_x[t]);
        return;
    }
    t -= 64 * 512;
    if (t < 64 * 1024) {                      // uhT[r][k] = u_h[k][r]
        int k = t >> 6, r = t & 63;
        uhT[r * 1024 + k] = f2bf(u_h[t]);
        return;
    }
    t -= 64 * 1024;
    if (t < 4096 * 128) {                     // Vc = [v_x | v_h] rows, bf16
        int n = t >> 7, q = t & 127;
        Vc[t] = f2bf(q < 64 ? v_x[n * 64 + q] : v_h[n * 64 + (q - 64)]);
        return;
    }
    t -= 4096 * 128;
    if (t < 1536 * 64) {                      // coef: 1536 waves, one j each
        const int wid = t >> 6, lane = t & 63;
        const float* U; const float* V; float* C; int j, JN;
        if (wid < 512) { U = u_x; V = v_x; C = coef_x; j = wid;       JN = 512;  }
        else           { U = u_h; V = v_h; C = coef_h; j = wid - 512; JN = 1024; }
        const float uv = U[(size_t)j * 64 + lane];
        float s[4];
#pragma unroll
        for (int g = 0; g < 4; ++g)
            s[g] = uv * V[(size_t)(g * H_ + j) * 64 + lane];
#pragma unroll
        for (int off = 32; off >= 1; off >>= 1)
#pragma unroll
            for (int g = 0; g < 4; ++g)
                s[g] += __shfl_xor(s[g], off, 64);
        if (lane == 0)
#pragma unroll
            for (int g = 0; g < 4; ++g)
                C[g * JN + j] = s[g];
        return;
    }
}

// ---------------------------------------------------------------------------
// Stage 1: P[b][0:64] = x @ u_x, P[b][64:128] = h @ u_h  (bf16 MFMA).
// 256-thr blocks (4 waves), 16 batch rows per block -> grid (512, 2).
// (Byte-identical to R2.)
// ---------------------------------------------------------------------------
__global__ __launch_bounds__(256) void stage1_kernel(
    const float* __restrict__ x, const float* __restrict__ h,
    const short* __restrict__ uxT, const short* __restrict__ uhT,
    short* __restrict__ P)
{
    __shared__ short At[16 * 136];
    const int w = threadIdx.x >> 6, lane = threadIdx.x & 63;
    const int quad = lane >> 4, lr = lane & 15;
    const int n0 = w * 16;

    const float* X; const short* UT; int K, co;
    if (blockIdx.y == 0) { X = x; UT = uxT; K = I_; co = 0; }
    else                 { X = h; UT = uhT; K = H_; co = 64; }

    const int b0 = blockIdx.x * 16;
    const int srow = threadIdx.x >> 4;
    const int scol = (threadIdx.x & 15) * 8;

    f32x4 acc = {};
    const short* bp = UT + (size_t)(n0 + lr) * K + quad * 8;
    const short* arow = At + lr * 136 + quad * 8;
    const float* srcbase = X + (size_t)(b0 + srow) * K + scol;

    float4 c0 = ((const float4*)(srcbase))[0];
    float4 c1 = ((const float4*)(srcbase))[1];

    for (int k0 = 0; k0 < K; k0 += 128) {
        s16x8 p;
        p[0] = f2bf(c0.x); p[1] = f2bf(c0.y); p[2] = f2bf(c0.z); p[3] = f2bf(c0.w);
        p[4] = f2bf(c1.x); p[5] = f2bf(c1.y); p[6] = f2bf(c1.z); p[7] = f2bf(c1.w);
        __syncthreads();
        *(s16x8*)(At + srow * 136 + scol) = p;
        __syncthreads();
        if (k0 + 128 < K) {
            c0 = ((const float4*)(srcbase + k0 + 128))[0];
            c1 = ((const float4*)(srcbase + k0 + 128))[1];
        }
#pragma unroll
        for (int ks = 0; ks < 4; ++ks) {
            bf16x8 bfrag = *(const bf16x8*)(bp + k0 + ks * 32);
            bf16x8 afrag = *(const bf16x8*)(arow + ks * 32);
            acc = __builtin_amdgcn_mfma_f32_16x16x32_bf16(afrag, bfrag, acc, 0, 0, 0);
        }
    }

#pragma unroll
    for (int r = 0; r < 4; ++r)
        P[(size_t)(b0 + quad * 4 + r) * 128 + co + n0 + lr] = f2bf(acc[r]);
}

// ---------------------------------------------------------------------------
// Stage 2: gates = P @ Vc^T with fused LSTM epilogue.
// EXACT R2 inner structure (best measured: 58 us) with ONE change: each wave
// now processes 8 m-tiles (128 batch rows) instead of 4, grid (64, 16) =
// 1024 workgroups (half of R2). Rationale: R2 measured only ~4.8 resident
// waves/CU (15%) despite VGPR=92 allowing 20 -> suspected workgroup
// dispatch/turnover limit. Doubling wave lifetime halves WG churn and
// amortizes the Vc/constant prologue over 2x work, leaving the memory
// access shapes byte-identical. If occupancy/dur don't move, the ~2 TB/s
// wall is a memory-system property and stage2 is at its practical ceiling.
// 256-thr blocks = 4 INDEPENDENT waves (no LDS, no barriers); block's 4
// waves cover 4 consecutive j-tiles at the same batch rows.
// ---------------------------------------------------------------------------
__global__ __launch_bounds__(256) void stage2_kernel(
    const short* __restrict__ P, const short* __restrict__ Vc,
    const float* __restrict__ x, const float* __restrict__ h,
    const float* __restrict__ c,
    const float* __restrict__ coef_x, const float* __restrict__ coef_h,
    const float* __restrict__ b_x, const float* __restrict__ b_h,
    const float* __restrict__ dia_x, const float* __restrict__ dia_h,
    float* __restrict__ out)
{
    const int lane = threadIdx.x & 63;
    const int wv   = threadIdx.x >> 6;
    const int quad = lane >> 4, lr = lane & 15;
    const int b0 = blockIdx.x * 128;                // rows shared by all 4 waves
    const int j0 = blockIdx.y * 64 + wv * 16;       // per-wave j-tile
    const int j = j0 + lr;
    const bool jx = (j < I_);

    // ---- B operand: 4 gates x 4 k-slices, resident in VGPRs for the wave's life
    bf16x8 bfr[4][4];
#pragma unroll
    for (int g = 0; g < 4; ++g)
#pragma unroll
        for (int ks = 0; ks < 4; ++ks)
            bfr[g][ks] = *(const bf16x8*)(Vc + (size_t)(g * H_ + j0 + lr) * 128 + ks * 32 + quad * 8);

    // per-j (lane-constant) small operands — L2-hot
    const float dx = jx ? dia_x[j] : 0.f;
    const float dh = dia_h[j];
    float cx[4], ch[4], bsum[4];
#pragma unroll
    for (int g = 0; g < 4; ++g) {
        cx[g]   = jx ? coef_x[g * I_ + j] : 0.f;
        ch[g]   = coef_h[g * H_ + j];
        bsum[g] = b_x[g * H_ + j] + b_h[g * H_ + j];
    }

    // prologue: A-fragments + epilogue operands for m-tile 0
    bf16x8 a[4];
#pragma unroll
    for (int ks = 0; ks < 4; ++ks)
        a[ks] = *(const bf16x8*)(P + (size_t)(b0 + lr) * 128 + ks * 32 + quad * 8);
    float xv[4], hv[4], cv[4];
#pragma unroll
    for (int r = 0; r < 4; ++r) {
        const int brow = b0 + quad * 4 + r;
        cv[r] = c[(size_t)brow * H_ + j];
        hv[r] = h[(size_t)brow * H_ + j];
        xv[r] = jx ? x[(size_t)brow * I_ + j] : 0.f;
    }

    for (int mt = 0; mt < 8; ++mt) {
        // prefetch next m-tile's A-fragments + epilogue operands
        bf16x8 an[4];
        float xn[4], hn[4], cn2[4];
        if (mt < 7) {
            const int rb = b0 + (mt + 1) * 16;
#pragma unroll
            for (int ks = 0; ks < 4; ++ks)
                an[ks] = *(const bf16x8*)(P + (size_t)(rb + lr) * 128 + ks * 32 + quad * 8);
#pragma unroll
            for (int r = 0; r < 4; ++r) {
                const int brow = rb + quad * 4 + r;
                cn2[r] = c[(size_t)brow * H_ + j];
                hn[r]  = h[(size_t)brow * H_ + j];
                xn[r]  = jx ? x[(size_t)brow * I_ + j] : 0.f;
            }
        }

        // MFMA: A and B both from registers — zero memory ops in the loop
        f32x4 acc[4] = {};
#pragma unroll
        for (int ks = 0; ks < 4; ++ks)
#pragma unroll
            for (int g = 0; g < 4; ++g)
                acc[g] = __builtin_amdgcn_mfma_f32_16x16x32_bf16(a[ks], bfr[g][ks], acc[g], 0, 0, 0);

        // epilogue for this m-tile
#pragma unroll
        for (int r = 0; r < 4; ++r) {
            const int brow = b0 + mt * 16 + quad * 4 + r;
            const float xe = xv[r], he = hv[r];
            const float z  = dx * xe + dh * he;

            const float g0 = acc[0][r] - xe * cx[0] - he * ch[0] + bsum[0] + z;
            const float g1 = acc[1][r] - xe * cx[1] - he * ch[1] + bsum[1] + z;
            const float g2 = acc[2][r] - xe * cx[2] - he * ch[2] + bsum[2] + z;
            const float g3 = acc[3][r] - xe * cx[3] - he * ch[3] + bsum[3] + z;

            const float ig = sigmoidf_(g0);
            const float fg = sigmoidf_(g1);
            const float og = sigmoidf_(g2);
            const float ng = tanhf_(g3);

            const float cn = fg * cv[r] + ig * ng;
            const float hnv = og * tanhf_(cn);

            out[(size_t)brow * H_ + j] = hnv;
            out[(size_t)B_ * H_ + (size_t)brow * H_ + j] = cn;
        }

        if (mt < 7) {
#pragma unroll
            for (int ks = 0; ks < 4; ++ks) a[ks] = an[ks];
#pragma unroll
            for (int r = 0; r < 4; ++r) { xv[r] = xn[r]; hv[r] = hn[r]; cv[r] = cn2[r]; }
        }
    }
}

// ---------------------------------------------------------------------------
extern "C" void kernel_launch(void* const* d_in, const int* in_sizes, int n_in,
                              void* d_out, int out_size, void* d_ws, size_t ws_size,
                              hipStream_t stream) {
    const float* x     = (const float*)d_in[0];
    const float* h     = (const float*)d_in[1];
    const float* c     = (const float*)d_in[2];
    const float* u_x   = (const float*)d_in[3];
    const float* u_h   = (const float*)d_in[4];
    const float* v_x   = (const float*)d_in[5];
    const float* v_h   = (const float*)d_in[6];
    const float* b_x   = (const float*)d_in[7];
    const float* b_h   = (const float*)d_in[8];
    const float* dia_x = (const float*)d_in[9];
    const float* dia_h = (const float*)d_in[10];
    float* out = (float*)d_out;

    char* ws = (char*)d_ws;
    short* P      = (short*)(ws);                                    // 2,097,152 B
    short* uxT    = (short*)(ws + 2097152);                          //    65,536
    short* uhT    = (short*)(ws + 2097152 + 65536);                  //   131,072
    short* Vc     = (short*)(ws + 2097152 + 65536 + 131072);         // 1,048,576
    float* coef_x = (float*)(ws + 2097152 + 65536 + 131072 + 1048576);
    float* coef_h = (float*)(ws + 2097152 + 65536 + 131072 + 1048576 + 8192);

    prep_kernel<<<2816, 256, 0, stream>>>(u_x, u_h, v_x, v_h, uxT, uhT, Vc, coef_x, coef_h);
    stage1_kernel<<<dim3(512, 2), 256, 0, stream>>>(x, h, uxT, uhT, P);
    stage2_kernel<<<dim3(64, 16), 256, 0, stream>>>(P, Vc, x, h, c,
                                                    coef_x, coef_h, b_x, b_h,
                                                    dia_x, dia_h, out);
}

// Round 7
// 184.702 us; speedup vs baseline: 1.2743x; 1.0440x over previous
//
#include <hip/hip_runtime.h>
#include <hip/hip_bf16.h>

#define B_ 8192
#define I_ 512
#define H_ 1024
#define R_ 64

typedef __bf16 bf16x8 __attribute__((ext_vector_type(8)));
typedef short  s16x8  __attribute__((ext_vector_type(8)));
typedef float  f32x4  __attribute__((ext_vector_type(4)));

static __device__ __forceinline__ short f2bf(float f) {
    union { float f; unsigned u; } v; v.f = f;
    unsigned r = v.u + 0x7fffu + ((v.u >> 16) & 1u);
    return (short)(r >> 16);
}
// v_rcp_f32 (~1 ulp) instead of IEEE divide (no -ffast-math in harness).
static __device__ __forceinline__ float frcp_(float x) {
#if __has_builtin(__builtin_amdgcn_rcpf)
    return __builtin_amdgcn_rcpf(x);
#else
    float r; asm("v_rcp_f32 %0, %1" : "=v"(r) : "v"(x)); return r;
#endif
}
static __device__ __forceinline__ float sigmoidf_(float v) {
    return frcp_(1.f + __expf(-v));
}
static __device__ __forceinline__ float tanhf_(float v) {
    return 2.f * frcp_(1.f + __expf(-2.f * v)) - 1.f;
}

// ---------------------------------------------------------------------------
// Prep: uxT[64][512], uhT[64][1024], Vc[4096][128] (all bf16), coef_x[4][512],
// coef_h[4][1024] (f32). Coef section: one wave per j, lanes = rank r.
// (Byte-identical to R2/R6.)
// ---------------------------------------------------------------------------
__global__ __launch_bounds__(256) void prep_kernel(
    const float* __restrict__ u_x, const float* __restrict__ u_h,
    const float* __restrict__ v_x, const float* __restrict__ v_h,
    short* __restrict__ uxT, short* __restrict__ uhT, short* __restrict__ Vc,
    float* __restrict__ coef_x, float* __restrict__ coef_h)
{
    int t = blockIdx.x * 256 + threadIdx.x;
    if (t < 64 * 512) {                       // uxT[r][k] = u_x[k][r], coalesced read
        int k = t >> 6, r = t & 63;
        uxT[r * 512 + k] = f2bf(u_x[t]);
        return;
    }
    t -= 64 * 512;
    if (t < 64 * 1024) {                      // uhT[r][k] = u_h[k][r]
        int k = t >> 6, r = t & 63;
        uhT[r * 1024 + k] = f2bf(u_h[t]);
        return;
    }
    t -= 64 * 1024;
    if (t < 4096 * 128) {                     // Vc = [v_x | v_h] rows, bf16
        int n = t >> 7, q = t & 127;
        Vc[t] = f2bf(q < 64 ? v_x[n * 64 + q] : v_h[n * 64 + (q - 64)]);
        return;
    }
    t -= 4096 * 128;
    if (t < 1536 * 64) {                      // coef: 1536 waves, one j each
        const int wid = t >> 6, lane = t & 63;
        const float* U; const float* V; float* C; int j, JN;
        if (wid < 512) { U = u_x; V = v_x; C = coef_x; j = wid;       JN = 512;  }
        else           { U = u_h; V = v_h; C = coef_h; j = wid - 512; JN = 1024; }
        const float uv = U[(size_t)j * 64 + lane];
        float s[4];
#pragma unroll
        for (int g = 0; g < 4; ++g)
            s[g] = uv * V[(size_t)(g * H_ + j) * 64 + lane];
#pragma unroll
        for (int off = 32; off >= 1; off >>= 1)
#pragma unroll
            for (int g = 0; g < 4; ++g)
                s[g] += __shfl_xor(s[g], off, 64);
        if (lane == 0)
#pragma unroll
            for (int g = 0; g < 4; ++g)
                C[g * JN + j] = s[g];
        return;
    }
}

// ---------------------------------------------------------------------------
// Stage 1: P[b][0:64] = x @ u_x, P[b][64:128] = h @ u_h  (bf16 MFMA).
// (Byte-identical to R2/R6.)
// ---------------------------------------------------------------------------
__global__ __launch_bounds__(256) void stage1_kernel(
    const float* __restrict__ x, const float* __restrict__ h,
    const short* __restrict__ uxT, const short* __restrict__ uhT,
    short* __restrict__ P)
{
    __shared__ short At[16 * 136];
    const int w = threadIdx.x >> 6, lane = threadIdx.x & 63;
    const int quad = lane >> 4, lr = lane & 15;
    const int n0 = w * 16;

    const float* X; const short* UT; int K, co;
    if (blockIdx.y == 0) { X = x; UT = uxT; K = I_; co = 0; }
    else                 { X = h; UT = uhT; K = H_; co = 64; }

    const int b0 = blockIdx.x * 16;
    const int srow = threadIdx.x >> 4;
    const int scol = (threadIdx.x & 15) * 8;

    f32x4 acc = {};
    const short* bp = UT + (size_t)(n0 + lr) * K + quad * 8;
    const short* arow = At + lr * 136 + quad * 8;
    const float* srcbase = X + (size_t)(b0 + srow) * K + scol;

    float4 c0 = ((const float4*)(srcbase))[0];
    float4 c1 = ((const float4*)(srcbase))[1];

    for (int k0 = 0; k0 < K; k0 += 128) {
        s16x8 p;
        p[0] = f2bf(c0.x); p[1] = f2bf(c0.y); p[2] = f2bf(c0.z); p[3] = f2bf(c0.w);
        p[4] = f2bf(c1.x); p[5] = f2bf(c1.y); p[6] = f2bf(c1.z); p[7] = f2bf(c1.w);
        __syncthreads();
        *(s16x8*)(At + srow * 136 + scol) = p;
        __syncthreads();
        if (k0 + 128 < K) {
            c0 = ((const float4*)(srcbase + k0 + 128))[0];
            c1 = ((const float4*)(srcbase + k0 + 128))[1];
        }
#pragma unroll
        for (int ks = 0; ks < 4; ++ks) {
            bf16x8 bfrag = *(const bf16x8*)(bp + k0 + ks * 32);
            bf16x8 afrag = *(const bf16x8*)(arow + ks * 32);
            acc = __builtin_amdgcn_mfma_f32_16x16x32_bf16(afrag, bfrag, acc, 0, 0, 0);
        }
    }

#pragma unroll
    for (int r = 0; r < 4; ++r)
        P[(size_t)(b0 + quad * 4 + r) * 128 + co + n0 + lr] = f2bf(acc[r]);
}

// ---------------------------------------------------------------------------
// Stage 2: gates = P @ Vc^T + fused LSTM epilogue, LDS-STAGED epilogue I/O.
// Compute structure = R6 (best: Vc-in-VGPR, P-fragments, same MFMA/math).
// NEW: all x/h/c reads and h'/c' writes go through LDS with cooperative
// block-wide float4 transfers: thread t moves (row t/16, j (t%16)*4) of the
// 16x64 tile, so each WAVE instruction covers 4 rows x 256 B fully-aligned
// CONTIGUOUS chunks (whole 128 B lines, no cross-wave line completion).
// This is the one variable R0-R6 never changed (all issued <=64 B/row
// fragments per instr) while BW stayed pinned at ~2 TB/s with all pipes
// idle. Per-lane scalar access moves to LDS (padded stride 68 -> 2-way max).
// Pipeline per m-tile: MFMA -> barrier -> issue next staging loads + P
// prefetch -> coop-store prev out tile -> epilogue (LDS) -> ds_write staged.
// One barrier per m-tile; in/out tiles double-buffered. LDS 43.5 KB/block.
// Grid (64, 16), 256 thr = 4 waves, wave wv owns j-tile j0b + wv*16.
// ---------------------------------------------------------------------------
__global__ __launch_bounds__(256) void stage2_kernel(
    const short* __restrict__ P, const short* __restrict__ Vc,
    const float* __restrict__ x, const float* __restrict__ h,
    const float* __restrict__ c,
    const float* __restrict__ coef_x, const float* __restrict__ coef_h,
    const float* __restrict__ b_x, const float* __restrict__ b_h,
    const float* __restrict__ dia_x, const float* __restrict__ dia_h,
    float* __restrict__ out)
{
    __shared__ float inx[2][16 * 68];
    __shared__ float inh[2][16 * 68];
    __shared__ float inc[2][16 * 68];
    __shared__ float oh_[2][16 * 68];
    __shared__ float oc_[2][16 * 68];

    const int tid  = threadIdx.x;
    const int lane = tid & 63,  wv = tid >> 6;
    const int quad = lane >> 4, lr = lane & 15;
    const int b0  = blockIdx.x * 128;               // block's 128 batch rows
    const int j0b = blockIdx.y * 64;                // block's 64-wide j span
    const int j0  = j0b + wv * 16;                  // wave's j-tile
    const int j   = j0 + lr;
    const bool jx = (j0b < I_);                     // block-uniform

    const int srow = tid >> 4;                      // coop I/O: row 0..15
    const int scol = (tid & 15) * 4;                // coop I/O: j offset
    const int sidx = srow * 68 + scol;              // padded LDS float index
    const int jl   = wv * 16 + lr;                  // lane's local j column

    // ---- prologue: issue tile-0 staging loads FIRST (longest latency)
    f32x4 sx = {}, sh, sc;
    {
        const int gr = b0 + srow;
        sc = *(const f32x4*)(c + (size_t)gr * H_ + j0b + scol);
        sh = *(const f32x4*)(h + (size_t)gr * H_ + j0b + scol);
        if (jx) sx = *(const f32x4*)(x + (size_t)gr * I_ + j0b + scol);
    }

    // ---- Vc fragments: 4 gates x 4 k-slices, VGPR-resident for block life
    bf16x8 bfr[4][4];
#pragma unroll
    for (int g = 0; g < 4; ++g)
#pragma unroll
        for (int ks = 0; ks < 4; ++ks)
            bfr[g][ks] = *(const bf16x8*)(Vc + (size_t)(g * H_ + j0 + lr) * 128 + ks * 32 + quad * 8);

    // per-j (lane-constant) small operands — L2-hot
    const float dx = jx ? dia_x[j] : 0.f;
    const float dh = dia_h[j];
    float cx[4], ch[4], bsum[4];
#pragma unroll
    for (int g = 0; g < 4; ++g) {
        cx[g]   = jx ? coef_x[g * I_ + j] : 0.f;
        ch[g]   = coef_h[g * H_ + j];
        bsum[g] = b_x[g * H_ + j] + b_h[g * H_ + j];
    }

    // P fragments for m-tile 0
    bf16x8 a[4];
#pragma unroll
    for (int ks = 0; ks < 4; ++ks)
        a[ks] = *(const bf16x8*)(P + (size_t)(b0 + lr) * 128 + ks * 32 + quad * 8);

    // tile-0 staged regs -> LDS buffer 0
    *(f32x4*)&inc[0][sidx] = sc;
    *(f32x4*)&inh[0][sidx] = sh;
    if (jx) *(f32x4*)&inx[0][sidx] = sx;

    for (int mt = 0; mt < 8; ++mt) {
        const int buf = mt & 1;

        // MFMA: all-register, D[b][j] (R6 layout)
        f32x4 acc[4] = {};
#pragma unroll
        for (int ks = 0; ks < 4; ++ks)
#pragma unroll
            for (int g = 0; g < 4; ++g)
                acc[g] = __builtin_amdgcn_mfma_f32_16x16x32_bf16(a[ks], bfr[g][ks], acc[g], 0, 0, 0);

        __syncthreads();   // tile mt input LDS ready; prev out tile visible

        // issue next-tile staging loads + P prefetch (hide under store+epilogue)
        bf16x8 an[4];
        if (mt < 7) {
            const int gr = b0 + (mt + 1) * 16 + srow;
            sc = *(const f32x4*)(c + (size_t)gr * H_ + j0b + scol);
            sh = *(const f32x4*)(h + (size_t)gr * H_ + j0b + scol);
            if (jx) sx = *(const f32x4*)(x + (size_t)gr * I_ + j0b + scol);
            const int rb = b0 + (mt + 1) * 16 + lr;
#pragma unroll
            for (int ks = 0; ks < 4; ++ks)
                an[ks] = *(const bf16x8*)(P + (size_t)rb * 128 + ks * 32 + quad * 8);
        }

        // cooperative store of PREVIOUS out tile: 4 rows x 256 B per wave instr
        if (mt > 0) {
            const int gr = b0 + (mt - 1) * 16 + srow;
            const int pb = (mt - 1) & 1;
            f32x4 vh = *(const f32x4*)&oh_[pb][sidx];
            f32x4 vc = *(const f32x4*)&oc_[pb][sidx];
            *(f32x4*)(out + (size_t)gr * H_ + j0b + scol) = vh;
            *(f32x4*)(out + (size_t)B_ * H_ + (size_t)gr * H_ + j0b + scol) = vc;
        }

        // epilogue: per-lane scalars from LDS (2-way bank max via stride 68)
#pragma unroll
        for (int r = 0; r < 4; ++r) {
            const int rl = quad * 4 + r;
            const float xe = jx ? inx[buf][rl * 68 + jl] : 0.f;
            const float he = inh[buf][rl * 68 + jl];
            const float ce = inc[buf][rl * 68 + jl];
            const float z  = dx * xe + dh * he;

            const float g0 = acc[0][r] - xe * cx[0] - he * ch[0] + bsum[0] + z;
            const float g1 = acc[1][r] - xe * cx[1] - he * ch[1] + bsum[1] + z;
            const float g2 = acc[2][r] - xe * cx[2] - he * ch[2] + bsum[2] + z;
            const float g3 = acc[3][r] - xe * cx[3] - he * ch[3] + bsum[3] + z;

            const float ig = sigmoidf_(g0);
            const float fg = sigmoidf_(g1);
            const float og = sigmoidf_(g2);
            const float ng = tanhf_(g3);

            const float cn  = fg * ce + ig * ng;
            const float hnv = og * tanhf_(cn);

            oh_[buf][rl * 68 + jl] = hnv;
            oc_[buf][rl * 68 + jl] = cn;
        }

        // staged regs -> next input buffer; advance P fragments
        if (mt < 7) {
            *(f32x4*)&inc[buf ^ 1][sidx] = sc;
            *(f32x4*)&inh[buf ^ 1][sidx] = sh;
            if (jx) *(f32x4*)&inx[buf ^ 1][sidx] = sx;
#pragma unroll
            for (int ks = 0; ks < 4; ++ks) a[ks] = an[ks];
        }
    }

    __syncthreads();
    {   // final out tile (mt = 7, buffer 1)
        const int gr = b0 + 7 * 16 + srow;
        f32x4 vh = *(const f32x4*)&oh_[1][sidx];
        f32x4 vc = *(const f32x4*)&oc_[1][sidx];
        *(f32x4*)(out + (size_t)gr * H_ + j0b + scol) = vh;
        *(f32x4*)(out + (size_t)B_ * H_ + (size_t)gr * H_ + j0b + scol) = vc;
    }
}

// ---------------------------------------------------------------------------
extern "C" void kernel_launch(void* const* d_in, const int* in_sizes, int n_in,
                              void* d_out, int out_size, void* d_ws, size_t ws_size,
                              hipStream_t stream) {
    const float* x     = (const float*)d_in[0];
    const float* h     = (const float*)d_in[1];
    const float* c     = (const float*)d_in[2];
    const float* u_x   = (const float*)d_in[3];
    const float* u_h   = (const float*)d_in[4];
    const float* v_x   = (const float*)d_in[5];
    const float* v_h   = (const float*)d_in[6];
    const float* b_x   = (const float*)d_in[7];
    const float* b_h   = (const float*)d_in[8];
    const float* dia_x = (const float*)d_in[9];
    const float* dia_h = (const float*)d_in[10];
    float* out = (float*)d_out;

    char* ws = (char*)d_ws;
    short* P      = (short*)(ws);                                    // 2,097,152 B
    short* uxT    = (short*)(ws + 2097152);                          //    65,536
    short* uhT    = (short*)(ws + 2097152 + 65536);                  //   131,072
    short* Vc     = (short*)(ws + 2097152 + 65536 + 131072);         // 1,048,576
    float* coef_x = (float*)(ws + 2097152 + 65536 + 131072 + 1048576);
    float* coef_h = (float*)(ws + 2097152 + 65536 + 131072 + 1048576 + 8192);

    prep_kernel<<<2816, 256, 0, stream>>>(u_x, u_h, v_x, v_h, uxT, uhT, Vc, coef_x, coef_h);
    stage1_kernel<<<dim3(512, 2), 256, 0, stream>>>(x, h, uxT, uhT, P);
    stage2_kernel<<<dim3(64, 16), 256, 0, stream>>>(P, Vc, x, h, c,
                                                    coef_x, coef_h, b_x, b_h,
                                                    dia_x, dia_h, out);
}